// Round 1
// baseline (817.700 us; speedup 1.0000x reference)
//
#include <hip/hip_runtime.h>

// Overdamped Langevin (OU process), bit-matching JAX's partitionable threefry RNG.
//
// Reference RNG chain (jax_threefry_partitionable=True, default since jax 0.4.36):
//   base key = (0, 42)
//   split(key, 1000):  key_j = threefry2x32_20((0,42), x=(0, j))        (both output words)
//   normal(key_j, (100000,3)): per flat element f:
//       (b0,b1) = threefry2x32_20(key_j, x=(0, f));  bits = b0 ^ b1
//       u01  = bitcast((bits>>9)|0x3f800000) - 1.0f            in [0,1)
//       u    = u01*2.0f + (-0.99999994f)  (hi-lo == 2.0f exactly in f32); clamped at lo
//       z    = sqrt(2) * erfinv(u)   (XLA/Giles polynomial, two branches)
//   step: x = x + ((-x)/gamma)*dt + sqrt(2*kT*dt/gamma)*z
// Frame 0 = x0; frame c (1..100) = state after c*store_every steps.

#define KCAP 2048  // LDS capacity for per-step keys (n_steps=1000 in harness)

__device__ __forceinline__ void tf2x32(unsigned k0, unsigned k1,
                                       unsigned x0, unsigned x1,
                                       unsigned &o0, unsigned &o1) {
    const unsigned ks2 = k0 ^ k1 ^ 0x1BD11BDAu;
    x0 += k0; x1 += k1;
#define RND(r) { x0 += x1; x1 = __builtin_rotateleft32(x1, r); x1 ^= x0; }
    RND(13) RND(15) RND(26) RND(6)
    x0 += k1;  x1 += ks2 + 1u;
    RND(17) RND(29) RND(16) RND(24)
    x0 += ks2; x1 += k0 + 2u;
    RND(13) RND(15) RND(26) RND(6)
    x0 += k0;  x1 += k1 + 3u;
    RND(17) RND(29) RND(16) RND(24)
    x0 += k1;  x1 += ks2 + 4u;
    RND(13) RND(15) RND(26) RND(6)
    x0 += ks2; x1 += k0 + 5u;
#undef RND
    o0 = x0; o1 = x1;
}

// bits -> N(0,1) matching jax.random.normal for float32.
__device__ __forceinline__ float bits_to_normal(unsigned bits) {
    const float LO = -0.99999994f;               // nextafter(-1, 0)
    unsigned fb = (bits >> 9) | 0x3f800000u;
    float f = __uint_as_float(fb) - 1.0f;        // [0, 1), 2^-23 grid
    float u = fmaf(f, 2.0f, LO);                 // f*2 is exact, so fma == mul+add
    u = fmaxf(u, LO);
    // XLA ErfInv (f32), Giles approximation
    float w = -__logf(fmaf(-u, u, 1.0f));        // -log(1 - u^2)
    float p;
    if (w < 5.0f) {
        w = w - 2.5f;
        p =              2.81022636e-08f;
        p = fmaf(p, w,   3.43273939e-07f);
        p = fmaf(p, w,  -3.5233877e-06f);
        p = fmaf(p, w,  -4.39150654e-06f);
        p = fmaf(p, w,   0.00021858087f);
        p = fmaf(p, w,  -0.00125372503f);
        p = fmaf(p, w,  -0.00417768164f);
        p = fmaf(p, w,   0.246640727f);
        p = fmaf(p, w,   1.50140941f);
    } else {
        w = sqrtf(w) - 3.0f;
        p =             -0.000200214257f;
        p = fmaf(p, w,   0.000100950558f);
        p = fmaf(p, w,   0.00134934322f);
        p = fmaf(p, w,  -0.00367342844f);
        p = fmaf(p, w,   0.00573950773f);
        p = fmaf(p, w,  -0.0076224613f);
        p = fmaf(p, w,   0.00943887047f);
        p = fmaf(p, w,   1.00167406f);
        p = fmaf(p, w,   2.83297682f);
    }
    return 1.41421356f * (p * u);                // sqrt(2) * erfinv(u)
}

__global__ __launch_bounds__(256) void OverdampedLangevin_62362925138458_kernel(
    const float* __restrict__ x0,
    const float* __restrict__ gamma_p,
    const float* __restrict__ kT_p,
    const float* __restrict__ dt_p,
    const int*   __restrict__ nsteps_p,
    const int*   __restrict__ store_p,
    float*       __restrict__ out,
    int E)
{
    __shared__ unsigned ksh[2 * KCAP];
    const int n_steps = *nsteps_p;
    const int store_every = *store_p;

    // Per-block: precompute per-step keys (split of key(42)) into LDS.
    const int nk = n_steps < KCAP ? n_steps : KCAP;
    for (int j = threadIdx.x; j < nk; j += blockDim.x) {
        unsigned b0, b1;
        tf2x32(0u, 42u, 0u, (unsigned)j, b0, b1);
        ksh[2 * j]     = b0;
        ksh[2 * j + 1] = b1;
    }
    __syncthreads();

    const int t = blockIdx.x * blockDim.x + threadIdx.x;
    if (t >= E) return;

    const float g  = gamma_p[0];
    const float kT = kT_p[0];
    const float dt = dt_p[0];
    const float scale = sqrtf(2.0f * kT * dt / g);   // same op order as reference
    const float a = dt / g;                          // x + (-x/g)*dt == x - a*x (1-ulp)

    float x = x0[t];
    out[t] = x;                                      // frame 0 = initial state

    int frame = 1, since = 0;
#pragma unroll 1
    for (int s = 0; s < n_steps; ++s) {
        unsigned k0, k1;
        if (s < KCAP) { k0 = ksh[2 * s]; k1 = ksh[2 * s + 1]; }
        else          { tf2x32(0u, 42u, 0u, (unsigned)s, k0, k1); }

        unsigned b0, b1;
        tf2x32(k0, k1, 0u, (unsigned)t, b0, b1);
        float n = bits_to_normal(b0 ^ b1);

        x = fmaf(scale, n, fmaf(-a, x, x));

        if (++since == store_every) {
            since = 0;
            out[(size_t)frame * (size_t)E + t] = x;
            ++frame;
        }
    }
}

extern "C" void kernel_launch(void* const* d_in, const int* in_sizes, int n_in,
                              void* d_out, int out_size, void* d_ws, size_t ws_size,
                              hipStream_t stream) {
    const float* x0    = (const float*)d_in[0];
    const float* gam   = (const float*)d_in[1];
    const float* kT    = (const float*)d_in[2];
    const float* dt    = (const float*)d_in[3];
    const int*   nst   = (const int*)d_in[4];
    const int*   sev   = (const int*)d_in[5];
    float*       out   = (float*)d_out;

    const int E = in_sizes[0];                 // 100000 * 3 = 300000
    const int blocks = (E + 255) / 256;
    OverdampedLangevin_62362925138458_kernel<<<blocks, 256, 0, stream>>>(
        x0, gam, kT, dt, nst, sev, out, E);
}

// Round 2
// 779.558 us; speedup vs baseline: 1.0489x; 1.0489x over previous
//
#include <hip/hip_runtime.h>

// Overdamped Langevin (OU process), bit-matching JAX's partitionable threefry RNG.
// See round-1 notes: base key (0,42); per-step keys = threefry((0,42),(0,j));
// per element f at step j: bits = b0^b1 of threefry(key_j,(0,f)); u in (-1,1);
// z = sqrt(2)*erfinv(u) via XLA/Giles poly; x <- x - (dt/g)x + sqrt(2 kT dt/g) z.
// Frame 0 = x0; frame c = state after c*store_every steps.

#define KCAP 1024  // per-step key slots in LDS (harness n_steps = 1000)

__device__ __forceinline__ void tf2x32(unsigned k0, unsigned k1,
                                       unsigned x0, unsigned x1,
                                       unsigned &o0, unsigned &o1) {
    const unsigned ks2 = k0 ^ k1 ^ 0x1BD11BDAu;
    x0 += k0; x1 += k1;
#define RND(r) { x0 += x1; x1 = __builtin_rotateleft32(x1, r); x1 ^= x0; }
    RND(13) RND(15) RND(26) RND(6)
    x0 += k1;  x1 += ks2 + 1u;
    RND(17) RND(29) RND(16) RND(24)
    x0 += ks2; x1 += k0 + 2u;
    RND(13) RND(15) RND(26) RND(6)
    x0 += k0;  x1 += k1 + 3u;
    RND(17) RND(29) RND(16) RND(24)
    x0 += k1;  x1 += ks2 + 4u;
    RND(13) RND(15) RND(26) RND(6)
    x0 += ks2; x1 += k0 + 5u;
#undef RND
    o0 = x0; o1 = x1;
}

// bits -> N(0,1), bit-identical to round-1 (which passed validation).
__device__ __forceinline__ float bits_to_normal(unsigned bits) {
    const float LO = -0.99999994f;               // nextafter(-1, 0)
#if __has_builtin(__builtin_amdgcn_alignbit)
    unsigned fb = __builtin_amdgcn_alignbit(0x7Fu, bits, 9u); // (0x7F:bits)>>9 == (bits>>9)|0x3f800000
#else
    unsigned fb = (bits >> 9) | 0x3f800000u;
#endif
    float f = __uint_as_float(fb) - 1.0f;        // [0, 1)
    float u = fmaf(f, 2.0f, LO);
    u = fmaxf(u, LO);
    float w = -__logf(fmaf(-u, u, 1.0f));        // -log(1 - u^2)
    float p;
    if (w < 5.0f) {
        w = w - 2.5f;
        p =              2.81022636e-08f;
        p = fmaf(p, w,   3.43273939e-07f);
        p = fmaf(p, w,  -3.5233877e-06f);
        p = fmaf(p, w,  -4.39150654e-06f);
        p = fmaf(p, w,   0.00021858087f);
        p = fmaf(p, w,  -0.00125372503f);
        p = fmaf(p, w,  -0.00417768164f);
        p = fmaf(p, w,   0.246640727f);
        p = fmaf(p, w,   1.50140941f);
    } else {
        w = sqrtf(w) - 3.0f;
        p =             -0.000200214257f;
        p = fmaf(p, w,   0.000100950558f);
        p = fmaf(p, w,   0.00134934322f);
        p = fmaf(p, w,  -0.00367342844f);
        p = fmaf(p, w,   0.00573950773f);
        p = fmaf(p, w,  -0.0076224613f);
        p = fmaf(p, w,   0.00943887047f);
        p = fmaf(p, w,   1.00167406f);
        p = fmaf(p, w,   2.83297682f);
    }
    return 1.41421356f * (p * u);                // sqrt(2) * erfinv(u)
}

// One Langevin step given the step's expanded key {k0, k1, ks2}.
// Injection constants +1..+5 fold into v_add3 with inline literals.
__device__ __forceinline__ float lang_step(float x, unsigned k0, unsigned k1,
                                           unsigned ks2, unsigned t,
                                           float scale, float na) {
    unsigned x0 = k0, x1 = k1 + t;
#define RND(r) { x0 += x1; x1 = __builtin_rotateleft32(x1, r); x1 ^= x0; }
    RND(13) RND(15) RND(26) RND(6)
    x0 += k1;  x1 += ks2 + 1u;
    RND(17) RND(29) RND(16) RND(24)
    x0 += ks2; x1 += k0 + 2u;
    RND(13) RND(15) RND(26) RND(6)
    x0 += k0;  x1 += k1 + 3u;
    RND(17) RND(29) RND(16) RND(24)
    x0 += k1;  x1 += ks2 + 4u;
    RND(13) RND(15) RND(26) RND(6)
    x0 += ks2; x1 += k0 + 5u;
#undef RND
    float n = bits_to_normal(x0 ^ x1);
    return fmaf(scale, n, fmaf(na, x, x));
}

__global__ __launch_bounds__(256) void OverdampedLangevin_62362925138458_kernel(
    const float* __restrict__ x0,
    const float* __restrict__ gamma_p,
    const float* __restrict__ kT_p,
    const float* __restrict__ dt_p,
    const int*   __restrict__ nsteps_p,
    const int*   __restrict__ store_p,
    float*       __restrict__ out,
    int E)
{
    __shared__ uint4 ksh[KCAP];   // {k0, k1, ks2, pad} per step
    const int n_steps = *nsteps_p;
    const int store_every = *store_p;

    // Per-block: per-step keys (split of key(42)) expanded into LDS.
    const int nk = n_steps < KCAP ? n_steps : KCAP;
    for (int j = threadIdx.x; j < nk; j += blockDim.x) {
        unsigned b0, b1;
        tf2x32(0u, 42u, 0u, (unsigned)j, b0, b1);
        ksh[j] = make_uint4(b0, b1, b0 ^ b1 ^ 0x1BD11BDAu, 0u);
    }
    __syncthreads();

    const unsigned t = blockIdx.x * blockDim.x + threadIdx.x;
    if ((int)t >= E) return;

    const float g  = gamma_p[0];
    const float kT = kT_p[0];
    const float dt = dt_p[0];
    const float scale = sqrtf(2.0f * kT * dt / g);
    const float na = -(dt / g);                  // x + (-x/g)*dt == fma(na, x, x)

    float x = x0[t];
    out[t] = x;                                  // frame 0

    if (store_every == 10 && n_steps % 10 == 0 && n_steps <= KCAP) {
        // Specialized: unrolled 10-step chunks, straight-line stores.
        const int n_chunks = n_steps / 10;
        float* op = out + (size_t)E + t;
        const uint4* kp = ksh;
        for (int c = 0; c < n_chunks; ++c) {
#pragma unroll
            for (int s = 0; s < 10; ++s) {
                const uint4 k = kp[s];
                x = lang_step(x, k.x, k.y, k.z, t, scale, na);
            }
            kp += 10;
            *op = x;
            op += (size_t)E;
        }
    } else {
        // Generic fallback (round-1 structure).
        int frame = 1, since = 0;
#pragma unroll 1
        for (int s = 0; s < n_steps; ++s) {
            unsigned k0, k1, ks2;
            if (s < KCAP) { uint4 k = ksh[s]; k0 = k.x; k1 = k.y; ks2 = k.z; }
            else {
                tf2x32(0u, 42u, 0u, (unsigned)s, k0, k1);
                ks2 = k0 ^ k1 ^ 0x1BD11BDAu;
            }
            x = lang_step(x, k0, k1, ks2, t, scale, na);
            if (++since == store_every) {
                since = 0;
                out[(size_t)frame * (size_t)E + t] = x;
                ++frame;
            }
        }
    }
}

extern "C" void kernel_launch(void* const* d_in, const int* in_sizes, int n_in,
                              void* d_out, int out_size, void* d_ws, size_t ws_size,
                              hipStream_t stream) {
    const float* x0    = (const float*)d_in[0];
    const float* gam   = (const float*)d_in[1];
    const float* kT    = (const float*)d_in[2];
    const float* dt    = (const float*)d_in[3];
    const int*   nst   = (const int*)d_in[4];
    const int*   sev   = (const int*)d_in[5];
    float*       out   = (float*)d_out;

    const int E = in_sizes[0];                 // 100000 * 3 = 300000
    const int blocks = (E + 255) / 256;
    OverdampedLangevin_62362925138458_kernel<<<blocks, 256, 0, stream>>>(
        x0, gam, kT, dt, nst, sev, out, E);
}

// Round 3
// 723.304 us; speedup vs baseline: 1.1305x; 1.0778x over previous
//
#include <hip/hip_runtime.h>

// Overdamped Langevin (OU), bit-matching JAX partitionable threefry RNG.
// base key (0,42); step key_j = threefry((0,42),(0,j)); per element f at step j:
// bits = b0^b1 of threefry(key_j,(0,f)); u in (-1,1); z = sqrt2*erfinv(u) (Giles);
// x <- x - (dt/g) x + sqrt(2 kT dt/g) z.  Frame 0 = x0, frame c = after c*store_every.
//
// VALU-issue-bound (R2: VALUBusy~102%, HBM 1.7%). This version minimizes issue
// slots/step: folded hash init, log2-domain erfinv prologue, wave-uniform rare
// branch (__any), sqrt2 folded into scale, keys via scalar loads from d_ws.

#define KCAP 1024  // per-step key slots (harness n_steps = 1000)

__device__ __forceinline__ unsigned rotl(unsigned v, int r) {
    return __builtin_rotateleft32(v, r);
}

__device__ __forceinline__ void tf2x32(unsigned k0, unsigned k1,
                                       unsigned x0, unsigned x1,
                                       unsigned &o0, unsigned &o1) {
    const unsigned ks2 = k0 ^ k1 ^ 0x1BD11BDAu;
    x0 += k0; x1 += k1;
#define RND(r) { x0 += x1; x1 = rotl(x1, r); x1 ^= x0; }
    RND(13) RND(15) RND(26) RND(6)
    x0 += k1;  x1 += ks2 + 1u;
    RND(17) RND(29) RND(16) RND(24)
    x0 += ks2; x1 += k0 + 2u;
    RND(13) RND(15) RND(26) RND(6)
    x0 += k0;  x1 += k1 + 3u;
    RND(17) RND(29) RND(16) RND(24)
    x0 += k1;  x1 += ks2 + 4u;
    RND(13) RND(15) RND(26) RND(6)
    x0 += ks2; x1 += k0 + 5u;
#undef RND
    o0 = x0; o1 = x1;
}

__device__ __forceinline__ float poly_lo(float w) {   // w = (-ln(1-u^2)) - 2.5
    float p =        2.81022636e-08f;
    p = fmaf(p, w,   3.43273939e-07f);
    p = fmaf(p, w,  -3.5233877e-06f);
    p = fmaf(p, w,  -4.39150654e-06f);
    p = fmaf(p, w,   0.00021858087f);
    p = fmaf(p, w,  -0.00125372503f);
    p = fmaf(p, w,  -0.00417768164f);
    p = fmaf(p, w,   0.246640727f);
    p = fmaf(p, w,   1.50140941f);
    return p;
}
__device__ __forceinline__ float poly_hi(float s) {   // s = sqrt(w) - 3
    float p =       -0.000200214257f;
    p = fmaf(p, s,   0.000100950558f);
    p = fmaf(p, s,   0.00134934322f);
    p = fmaf(p, s,  -0.00367342844f);
    p = fmaf(p, s,   0.00573950773f);
    p = fmaf(p, s,  -0.0076224613f);
    p = fmaf(p, s,   0.00943887047f);
    p = fmaf(p, s,   1.00167406f);
    p = fmaf(p, s,   2.83297682f);
    return p;
}

// One step. k = {k0, k1, ks2, k0+k1} (wave-uniform). ~92 VALU slots.
__device__ __forceinline__ float lang_step(float x, uint4 k, unsigned t,
                                           float scale2, float na) {
    unsigned x1 = k.y + t;                 // k1 + t
    unsigned x0 = k.w + t;                 // (k0+k1) + t == round-1 add, mov folded
    x1 = rotl(x1, 13) ^ x0;                // finish round 1
#define RND(r) { x0 += x1; x1 = rotl(x1, r); x1 ^= x0; }
    RND(15) RND(26) RND(6)
    x0 += k.y; x1 += k.z + 1u;
    RND(17) RND(29) RND(16) RND(24)
    x0 += k.z; x1 += k.x + 2u;
    RND(13) RND(15) RND(26) RND(6)
    x0 += k.x; x1 += k.y + 3u;
    RND(17) RND(29) RND(16) RND(24)
    x0 += k.y; x1 += k.z + 4u;
    RND(13) RND(15) RND(26) RND(6)
    x0 += k.z; x1 += k.x + 5u;
#undef RND
    unsigned bits = x0 ^ x1;

    // normal transform (log2 domain, folded constants; ulp-equal to R1's path)
    unsigned fb = (bits >> 9) | 0x3f800000u;            // v_alignbit pattern
    float F = __uint_as_float(fb);                      // [1,2)
    float u = fmaf(F, 2.0f, -3.0f);                     // == 2(F-1)+LO (+2^-24)
    u = fmaxf(u, -0.99999994f);
    float h = fmaf(-u, u, 1.0f);                        // 1 - u^2
#if __has_builtin(__builtin_amdgcn_logf)
    float l2 = __builtin_amdgcn_logf(h);                // log2(1-u^2)
#else
    float l2 = __log2f(h);
#endif
    float p;
    if (__builtin_expect(__any(l2 <= -7.2134752f), 0)) {   // any lane: w >= 5
        float w  = l2 * -0.69314718f;
        float p1 = poly_lo(w - 2.5f);
        float p2 = poly_hi(sqrtf(w) - 3.0f);
        p = (l2 > -7.2134752f) ? p1 : p2;
    } else {
        p = poly_lo(fmaf(l2, -0.69314718f, -2.5f));     // w - 2.5 in one fma
    }
    return fmaf(scale2, p * u, fmaf(na, x, x));         // scale2 = scale*sqrt2
}

__global__ __launch_bounds__(256) void expand_keys(uint4* __restrict__ kw) {
    unsigned j = blockIdx.x * 256 + threadIdx.x;
    if (j < KCAP) {
        unsigned b0, b1;
        tf2x32(0u, 42u, 0u, j, b0, b1);
        kw[j] = make_uint4(b0, b1, b0 ^ b1 ^ 0x1BD11BDAu, b0 + b1);
    }
}

template <bool GK>
__global__ __launch_bounds__(256) void OverdampedLangevin_62362925138458_kernel(
    const float* __restrict__ x0p,
    const float* __restrict__ gamma_p,
    const float* __restrict__ kT_p,
    const float* __restrict__ dt_p,
    const int*   __restrict__ nsteps_p,
    const int*   __restrict__ store_p,
    const uint4* __restrict__ kw,
    float*       __restrict__ out,
    int E)
{
    extern __shared__ uint4 ksh[];
    const int n_steps = *nsteps_p;
    const int store_every = *store_p;

    if (!GK) {  // LDS fallback when ws too small
        const int nk = n_steps < KCAP ? n_steps : KCAP;
        for (int j = threadIdx.x; j < nk; j += blockDim.x) {
            unsigned b0, b1;
            tf2x32(0u, 42u, 0u, (unsigned)j, b0, b1);
            ksh[j] = make_uint4(b0, b1, b0 ^ b1 ^ 0x1BD11BDAu, b0 + b1);
        }
        __syncthreads();
    }

    const unsigned t = blockIdx.x * blockDim.x + threadIdx.x;
    if ((int)t >= E) return;

    const float g  = gamma_p[0];
    const float kT = kT_p[0];
    const float dt = dt_p[0];
    const float scale2 = sqrtf(2.0f * kT * dt / g) * 1.41421356f;
    const float na = -(dt / g);

    float x = x0p[t];
    out[t] = x;                                  // frame 0

    if (store_every == 10 && n_steps % 10 == 0 && n_steps <= KCAP) {
        const int nc = n_steps / 10;
        float* op = out + (size_t)E + t;
        int idx = 0;
        for (int c = 0; c < nc; ++c) {
#pragma unroll
            for (int s = 0; s < 10; ++s) {
                const uint4 k = GK ? kw[idx + s] : ksh[idx + s];
                x = lang_step(x, k, t, scale2, na);
            }
            idx += 10;
            *op = x;
            op += (size_t)E;
        }
    } else {
        int frame = 1, since = 0;
#pragma unroll 1
        for (int s = 0; s < n_steps; ++s) {
            uint4 k;
            if (s < KCAP) k = GK ? kw[s] : ksh[s];
            else {
                unsigned b0, b1;
                tf2x32(0u, 42u, 0u, (unsigned)s, b0, b1);
                k = make_uint4(b0, b1, b0 ^ b1 ^ 0x1BD11BDAu, b0 + b1);
            }
            x = lang_step(x, k, t, scale2, na);
            if (++since == store_every) {
                since = 0;
                out[(size_t)frame * (size_t)E + t] = x;
                ++frame;
            }
        }
    }
}

extern "C" void kernel_launch(void* const* d_in, const int* in_sizes, int n_in,
                              void* d_out, int out_size, void* d_ws, size_t ws_size,
                              hipStream_t stream) {
    const float* x0    = (const float*)d_in[0];
    const float* gam   = (const float*)d_in[1];
    const float* kT    = (const float*)d_in[2];
    const float* dt    = (const float*)d_in[3];
    const int*   nst   = (const int*)d_in[4];
    const int*   sev   = (const int*)d_in[5];
    float*       out   = (float*)d_out;

    const int E = in_sizes[0];                 // 100000 * 3 = 300000
    const int blocks = (E + 255) / 256;

    if (ws_size >= KCAP * sizeof(uint4)) {
        uint4* kw = (uint4*)d_ws;
        expand_keys<<<(KCAP + 255) / 256, 256, 0, stream>>>(kw);
        OverdampedLangevin_62362925138458_kernel<true><<<blocks, 256, 0, stream>>>(
            x0, gam, kT, dt, nst, sev, kw, out, E);
    } else {
        OverdampedLangevin_62362925138458_kernel<false>
            <<<blocks, 256, KCAP * sizeof(uint4), stream>>>(
            x0, gam, kT, dt, nst, sev, nullptr, out, E);
    }
}

// Round 4
// 716.182 us; speedup vs baseline: 1.1417x; 1.0099x over previous
//
#include <hip/hip_runtime.h>

// Overdamped Langevin (OU), bit-matching JAX partitionable threefry RNG.
// base key (0,42); step key_j = threefry((0,42),(0,j)); per element f at step j:
// bits = b0^b1 of threefry(key_j,(0,f)); u in (-1,1); z = sqrt2*erfinv(u) (Giles);
// x <- x - (dt/g) x + sqrt(2 kT dt/g) z.  Frame 0 = x0, frame c = after c*store_every.
//
// VALU-issue-bound (R3: VALUBusy~98%, HBM 0.01%, VGPR=20). This version:
//  - per-step keys baked at COMPILE TIME into __constant__ (scalar s_load, no VMEM)
//  - chunk restructured as 10 independent normals then 20-fma state chain (ILP)

#define KCAP 1024  // compile-time key slots (harness n_steps = 1000)

// ---------- compile-time key table ----------
struct alignas(16) Rec { unsigned s, b, c, a; };  // s=k0+k1, b=k1, c=ks2, a=k0
struct KTable { Rec r[KCAP]; };

constexpr unsigned crotl(unsigned v, int r) { return (v << r) | (v >> (32 - r)); }

constexpr KTable gen_keys() {
    KTable t{};
    for (unsigned j = 0; j < KCAP; ++j) {
        // threefry2x32-20 with key (0,42), input (0, j)
        const unsigned k0 = 0u, k1 = 42u, ks2 = k0 ^ k1 ^ 0x1BD11BDAu;
        unsigned x0 = 0u + k0, x1 = j + k1;
        const int rots[20] = {13,15,26,6, 17,29,16,24, 13,15,26,6, 17,29,16,24, 13,15,26,6};
        int ri = 0;
        for (int blk = 0; blk < 5; ++blk) {
            for (int rr = 0; rr < 4; ++rr) { x0 += x1; x1 = crotl(x1, rots[ri++]); x1 ^= x0; }
            switch (blk) {
                case 0: x0 += k1;  x1 += ks2 + 1u; break;
                case 1: x0 += ks2; x1 += k0 + 2u;  break;
                case 2: x0 += k0;  x1 += k1 + 3u;  break;
                case 3: x0 += k1;  x1 += ks2 + 4u; break;
                case 4: x0 += ks2; x1 += k0 + 5u;  break;
            }
        }
        const unsigned b0 = x0, b1 = x1;
        t.r[j] = Rec{b0 + b1, b1, b0 ^ b1 ^ 0x1BD11BDAu, b0};
    }
    return t;
}

__constant__ KTable KTAB = gen_keys();

// ---------- device math ----------
__device__ __forceinline__ unsigned rotl(unsigned v, int r) {
    return __builtin_rotateleft32(v, r);
}

__device__ __forceinline__ float poly_lo(float w) {   // w = (-ln(1-u^2)) - 2.5
    float p =        2.81022636e-08f;
    p = fmaf(p, w,   3.43273939e-07f);
    p = fmaf(p, w,  -3.5233877e-06f);
    p = fmaf(p, w,  -4.39150654e-06f);
    p = fmaf(p, w,   0.00021858087f);
    p = fmaf(p, w,  -0.00125372503f);
    p = fmaf(p, w,  -0.00417768164f);
    p = fmaf(p, w,   0.246640727f);
    p = fmaf(p, w,   1.50140941f);
    return p;
}
__device__ __forceinline__ float poly_hi(float s) {   // s = sqrt(w) - 3
    float p =       -0.000200214257f;
    p = fmaf(p, s,   0.000100950558f);
    p = fmaf(p, s,   0.00134934322f);
    p = fmaf(p, s,  -0.00367342844f);
    p = fmaf(p, s,   0.00573950773f);
    p = fmaf(p, s,  -0.0076224613f);
    p = fmaf(p, s,   0.00943887047f);
    p = fmaf(p, s,   1.00167406f);
    p = fmaf(p, s,   2.83297682f);
    return p;
}

// z = erfinv-scaled normal core (without the wave-uniform scale factor).
__device__ __forceinline__ float normal_of(Rec k, unsigned t) {
    unsigned x1 = k.b + t;                 // k1 + t
    unsigned x0 = k.s + t;                 // (k0+k1) + t : round-1 add, mov folded
    x1 = rotl(x1, 13) ^ x0;                // finish round 1
#define RND(r) { x0 += x1; x1 = rotl(x1, r); x1 ^= x0; }
    RND(15) RND(26) RND(6)
    x0 += k.b; x1 += k.c + 1u;
    RND(17) RND(29) RND(16) RND(24)
    x0 += k.c; x1 += k.a + 2u;
    RND(13) RND(15) RND(26) RND(6)
    x0 += k.a; x1 += k.b + 3u;
    RND(17) RND(29) RND(16) RND(24)
    x0 += k.b; x1 += k.c + 4u;
    RND(13) RND(15) RND(26) RND(6)
    x0 += k.c; x1 += k.a + 5u;
#undef RND
    unsigned bits = x0 ^ x1;

#if __has_builtin(__builtin_amdgcn_alignbit)
    unsigned fb = __builtin_amdgcn_alignbit(0x7Fu, bits, 9u); // (bits>>9)|0x3f800000
#else
    unsigned fb = (bits >> 9) | 0x3f800000u;
#endif
    float F = __uint_as_float(fb);                      // [1,2)
    float u = fmaf(F, 2.0f, -3.0f);                     // == 2(F-1)+LO (+2^-24)
    u = fmaxf(u, -0.99999994f);
    float h = fmaf(-u, u, 1.0f);                        // 1 - u^2
#if __has_builtin(__builtin_amdgcn_logf)
    float l2 = __builtin_amdgcn_logf(h);                // log2(1-u^2)
#else
    float l2 = __log2f(h);
#endif
    float p;
    if (__builtin_expect(__any(l2 <= -7.2134752f), 0)) {   // any lane: w >= 5
        float w  = l2 * -0.69314718f;
        float p1 = poly_lo(w - 2.5f);
        float p2 = poly_hi(sqrtf(w) - 3.0f);
        p = (l2 > -7.2134752f) ? p1 : p2;
    } else {
        p = poly_lo(fmaf(l2, -0.69314718f, -2.5f));     // w - 2.5 in one fma
    }
    return p * u;                                       // caller applies scale*sqrt2
}

// on-the-fly key expansion (generic fallback, s >= KCAP)
__device__ __forceinline__ Rec make_key(unsigned j) {
    const unsigned k0 = 0u, k1 = 42u, ks2 = k0 ^ k1 ^ 0x1BD11BDAu;
    unsigned x0 = k0, x1 = j + k1;
#define RND(r) { x0 += x1; x1 = rotl(x1, r); x1 ^= x0; }
    RND(13) RND(15) RND(26) RND(6)
    x0 += k1;  x1 += ks2 + 1u;
    RND(17) RND(29) RND(16) RND(24)
    x0 += ks2; x1 += k0 + 2u;
    RND(13) RND(15) RND(26) RND(6)
    x0 += k0;  x1 += k1 + 3u;
    RND(17) RND(29) RND(16) RND(24)
    x0 += k1;  x1 += ks2 + 4u;
    RND(13) RND(15) RND(26) RND(6)
    x0 += ks2; x1 += k0 + 5u;
#undef RND
    Rec r; r.s = x0 + x1; r.b = x1; r.c = x0 ^ x1 ^ 0x1BD11BDAu; r.a = x0;
    return r;
}

__global__ __launch_bounds__(256) void OverdampedLangevin_62362925138458_kernel(
    const float* __restrict__ x0p,
    const float* __restrict__ gamma_p,
    const float* __restrict__ kT_p,
    const float* __restrict__ dt_p,
    const int*   __restrict__ nsteps_p,
    const int*   __restrict__ store_p,
    float*       __restrict__ out,
    int E)
{
    const int n_steps = *nsteps_p;
    const int store_every = *store_p;

    const unsigned t = blockIdx.x * blockDim.x + threadIdx.x;
    if ((int)t >= E) return;

    const float g  = gamma_p[0];
    const float kT = kT_p[0];
    const float dt = dt_p[0];
    const float scale2 = sqrtf(2.0f * kT * dt / g) * 1.41421356f;
    const float na = -(dt / g);

    float x = x0p[t];
    out[t] = x;                                  // frame 0

    if (store_every == 10 && n_steps % 10 == 0 && n_steps <= KCAP) {
        const int nc = n_steps / 10;
        float* op = out + (size_t)E + t;
        int idx = 0;
        for (int c = 0; c < nc; ++c) {
            // Phase 1: 10 independent normals (hashes don't depend on x) — ILP.
            float z[10];
#pragma unroll
            for (int s = 0; s < 10; ++s)
                z[s] = normal_of(KTAB.r[idx + s], t);
            // Phase 2: 20-fma state chain.
#pragma unroll
            for (int s = 0; s < 10; ++s)
                x = fmaf(scale2, z[s], fmaf(na, x, x));
            idx += 10;
            *op = x;
            op += (size_t)E;
        }
    } else {
        int frame = 1, since = 0;
#pragma unroll 1
        for (int s = 0; s < n_steps; ++s) {
            Rec k = (s < KCAP) ? KTAB.r[s] : make_key((unsigned)s);
            float zz = normal_of(k, t);
            x = fmaf(scale2, zz, fmaf(na, x, x));
            if (++since == store_every) {
                since = 0;
                out[(size_t)frame * (size_t)E + t] = x;
                ++frame;
            }
        }
    }
}

extern "C" void kernel_launch(void* const* d_in, const int* in_sizes, int n_in,
                              void* d_out, int out_size, void* d_ws, size_t ws_size,
                              hipStream_t stream) {
    const float* x0    = (const float*)d_in[0];
    const float* gam   = (const float*)d_in[1];
    const float* kT    = (const float*)d_in[2];
    const float* dt    = (const float*)d_in[3];
    const int*   nst   = (const int*)d_in[4];
    const int*   sev   = (const int*)d_in[5];
    float*       out   = (float*)d_out;

    const int E = in_sizes[0];                 // 100000 * 3 = 300000
    const int blocks = (E + 255) / 256;
    OverdampedLangevin_62362925138458_kernel<<<blocks, 256, 0, stream>>>(
        x0, gam, kT, dt, nst, sev, out, E);
}

// Round 5
// 708.059 us; speedup vs baseline: 1.1548x; 1.0115x over previous
//
#include <hip/hip_runtime.h>

// Overdamped Langevin (OU), bit-matching JAX partitionable threefry RNG.
// base key (0,42); step key_j = threefry((0,42),(0,j)); per element f at step j:
// bits = b0^b1 of threefry(key_j,(0,f)); u in (-1,1); z = sqrt2*erfinv(u) (Giles);
// x <- x - (dt/g) x + sqrt(2 kT dt/g) z.  Frame 0 = x0, frame c = after c*store_every.
//
// VALU-issue-bound. R5 levers: (1) force all 20 threefry rotates to
// v_alignbit_b32 via __builtin_amdgcn_alignbit; (2) pin float constants in
// VGPRs (VOP3 can't encode literals on gfx9-lineage) so every fma is reg-reg.

#define KCAP 1024  // compile-time key slots (harness n_steps = 1000)

#if __has_builtin(__builtin_amdgcn_alignbit)
#define ROTL(x, r) __builtin_amdgcn_alignbit((x), (x), 32u - (r))
#define SPLICE(bits) __builtin_amdgcn_alignbit(0x7Fu, (bits), 9u)  // (bits>>9)|0x3f800000
#else
#define ROTL(x, r) __builtin_rotateleft32((x), (r))
#define SPLICE(bits) (((bits) >> 9) | 0x3f800000u)
#endif

// ---------- compile-time key table ----------
struct alignas(16) Rec { unsigned s, b, c, a; };  // s=k0+k1, b=k1, c=ks2, a=k0
struct KTable { Rec r[KCAP]; };

constexpr unsigned crotl(unsigned v, int r) { return (v << r) | (v >> (32 - r)); }

constexpr KTable gen_keys() {
    KTable t{};
    for (unsigned j = 0; j < KCAP; ++j) {
        const unsigned k0 = 0u, k1 = 42u, ks2 = k0 ^ k1 ^ 0x1BD11BDAu;
        unsigned x0 = 0u + k0, x1 = j + k1;
        const int rots[20] = {13,15,26,6, 17,29,16,24, 13,15,26,6, 17,29,16,24, 13,15,26,6};
        int ri = 0;
        for (int blk = 0; blk < 5; ++blk) {
            for (int rr = 0; rr < 4; ++rr) { x0 += x1; x1 = crotl(x1, rots[ri++]); x1 ^= x0; }
            switch (blk) {
                case 0: x0 += k1;  x1 += ks2 + 1u; break;
                case 1: x0 += ks2; x1 += k0 + 2u;  break;
                case 2: x0 += k0;  x1 += k1 + 3u;  break;
                case 3: x0 += k1;  x1 += ks2 + 4u; break;
                case 4: x0 += ks2; x1 += k0 + 5u;  break;
            }
        }
        const unsigned b0 = x0, b1 = x1;
        t.r[j] = Rec{b0 + b1, b1, b0 ^ b1 ^ 0x1BD11BDAu, b0};
    }
    return t;
}

__constant__ KTable KTAB = gen_keys();

// VGPR-pinned float constants (VOP3 literals are illegal on gfx9-lineage;
// without pinning, low-VGPR schedules re-materialize these every use).
struct Consts {
    float P0, P1, P2, P3, P4, P5, P6, P7, P8;   // Giles lo-branch poly
    float NLN2, M25, M3, LO;                    // -ln2, -2.5, -3.0, nextafter(-1,0)
};

__device__ __forceinline__ float poly_lo(float w, const Consts& cc) {
    float p = cc.P0;
    p = fmaf(p, w, cc.P1);
    p = fmaf(p, w, cc.P2);
    p = fmaf(p, w, cc.P3);
    p = fmaf(p, w, cc.P4);
    p = fmaf(p, w, cc.P5);
    p = fmaf(p, w, cc.P6);
    p = fmaf(p, w, cc.P7);
    p = fmaf(p, w, cc.P8);
    return p;
}
__device__ __forceinline__ float poly_hi(float s) {   // rare path, literals ok
    float p =       -0.000200214257f;
    p = fmaf(p, s,   0.000100950558f);
    p = fmaf(p, s,   0.00134934322f);
    p = fmaf(p, s,  -0.00367342844f);
    p = fmaf(p, s,   0.00573950773f);
    p = fmaf(p, s,  -0.0076224613f);
    p = fmaf(p, s,   0.00943887047f);
    p = fmaf(p, s,   1.00167406f);
    p = fmaf(p, s,   2.83297682f);
    return p;
}

// erfinv-core normal (caller applies wave-uniform scale*sqrt2).
__device__ __forceinline__ float normal_of(Rec k, unsigned t, const Consts& cc) {
    unsigned x0 = k.s + t;                 // (k0+k1) + t : round-1 add, mov folded
    unsigned x1 = ROTL(k.b + t, 13) ^ x0;  // finish round 1
#define RND(r) { x0 += x1; x1 = ROTL(x1, r) ^ x0; }
    RND(15) RND(26) RND(6)
    x0 += k.b; x1 += k.c + 1u;
    RND(17) RND(29) RND(16) RND(24)
    x0 += k.c; x1 += k.a + 2u;
    RND(13) RND(15) RND(26) RND(6)
    x0 += k.a; x1 += k.b + 3u;
    RND(17) RND(29) RND(16) RND(24)
    x0 += k.b; x1 += k.c + 4u;
    RND(13) RND(15) RND(26) RND(6)
    x0 += k.c; x1 += k.a + 5u;
#undef RND
    unsigned bits = x0 ^ x1;

    float F = __uint_as_float(SPLICE(bits));            // [1,2)
    float u = fmaf(F, 2.0f, cc.M3);                     // == 2(F-1)+LO (+2^-24)
    u = fmaxf(u, cc.LO);
    float h = fmaf(-u, u, 1.0f);                        // 1 - u^2
    float l2 = __log2f(h);                              // v_log_f32
    float p;
    if (__builtin_expect(__any(l2 <= -7.2134752f), 0)) {   // any lane: w >= 5
        float w  = l2 * cc.NLN2;
        float p1 = poly_lo(w + cc.M25, cc);
        float p2 = poly_hi(sqrtf(w) + cc.M3);
        p = (l2 > -7.2134752f) ? p1 : p2;
    } else {
        p = poly_lo(fmaf(l2, cc.NLN2, cc.M25), cc);     // w - 2.5 in one fma
    }
    return p * u;
}

// on-the-fly key expansion (generic fallback, s >= KCAP)
__device__ __forceinline__ Rec make_key(unsigned j) {
    const unsigned k0 = 0u, k1 = 42u, ks2 = k0 ^ k1 ^ 0x1BD11BDAu;
    unsigned x0 = k0, x1 = j + k1;
#define RND(r) { x0 += x1; x1 = ROTL(x1, r) ^ x0; }
    RND(13) RND(15) RND(26) RND(6)
    x0 += k1;  x1 += ks2 + 1u;
    RND(17) RND(29) RND(16) RND(24)
    x0 += ks2; x1 += k0 + 2u;
    RND(13) RND(15) RND(26) RND(6)
    x0 += k0;  x1 += k1 + 3u;
    RND(17) RND(29) RND(16) RND(24)
    x0 += k1;  x1 += ks2 + 4u;
    RND(13) RND(15) RND(26) RND(6)
    x0 += ks2; x1 += k0 + 5u;
#undef RND
    Rec r; r.s = x0 + x1; r.b = x1; r.c = x0 ^ x1 ^ 0x1BD11BDAu; r.a = x0;
    return r;
}

__global__ __launch_bounds__(256) void OverdampedLangevin_62362925138458_kernel(
    const float* __restrict__ x0p,
    const float* __restrict__ gamma_p,
    const float* __restrict__ kT_p,
    const float* __restrict__ dt_p,
    const int*   __restrict__ nsteps_p,
    const int*   __restrict__ store_p,
    float*       __restrict__ out,
    int E)
{
    const int n_steps = *nsteps_p;
    const int store_every = *store_p;

    const unsigned t = blockIdx.x * blockDim.x + threadIdx.x;
    if ((int)t >= E) return;

    const float g  = gamma_p[0];
    const float kT = kT_p[0];
    const float dt = dt_p[0];
    float scale2 = sqrtf(2.0f * kT * dt / g) * 1.41421356f;
    float na = -(dt / g);

    Consts cc{2.81022636e-08f,  3.43273939e-07f, -3.5233877e-06f,
             -4.39150654e-06f,  0.00021858087f,  -0.00125372503f,
             -0.00417768164f,   0.246640727f,     1.50140941f,
             -0.69314718f,     -2.5f,            -3.0f, -0.99999994f};
    // Pin into VGPRs: reg-reg VOP3 fmas, no per-use re-materialization.
    asm("" : "+v"(cc.P0), "+v"(cc.P1), "+v"(cc.P2), "+v"(cc.P3), "+v"(cc.P4),
             "+v"(cc.P5), "+v"(cc.P6), "+v"(cc.P7), "+v"(cc.P8),
             "+v"(cc.NLN2), "+v"(cc.M25), "+v"(cc.M3), "+v"(cc.LO),
             "+v"(scale2), "+v"(na));

    float x = x0p[t];
    out[t] = x;                                  // frame 0

    if (store_every == 10 && n_steps % 10 == 0 && n_steps <= KCAP) {
        const int nc = n_steps / 10;
        float* op = out + (size_t)E + t;
        int idx = 0;
        for (int c = 0; c < nc; ++c) {
#pragma unroll
            for (int s = 0; s < 10; ++s) {
                float z = normal_of(KTAB.r[idx + s], t, cc);
                x = fmaf(scale2, z, fmaf(na, x, x));
            }
            idx += 10;
            *op = x;
            op += (size_t)E;
        }
    } else {
        int frame = 1, since = 0;
#pragma unroll 1
        for (int s = 0; s < n_steps; ++s) {
            Rec k = (s < KCAP) ? KTAB.r[s] : make_key((unsigned)s);
            float z = normal_of(k, t, cc);
            x = fmaf(scale2, z, fmaf(na, x, x));
            if (++since == store_every) {
                since = 0;
                out[(size_t)frame * (size_t)E + t] = x;
                ++frame;
            }
        }
    }
}

extern "C" void kernel_launch(void* const* d_in, const int* in_sizes, int n_in,
                              void* d_out, int out_size, void* d_ws, size_t ws_size,
                              hipStream_t stream) {
    const float* x0    = (const float*)d_in[0];
    const float* gam   = (const float*)d_in[1];
    const float* kT    = (const float*)d_in[2];
    const float* dt    = (const float*)d_in[3];
    const int*   nst   = (const int*)d_in[4];
    const int*   sev   = (const int*)d_in[5];
    float*       out   = (float*)d_out;

    const int E = in_sizes[0];                 // 100000 * 3 = 300000
    const int blocks = (E + 255) / 256;
    OverdampedLangevin_62362925138458_kernel<<<blocks, 256, 0, stream>>>(
        x0, gam, kT, dt, nst, sev, out, E);
}